// Round 11
// baseline (349.098 us; speedup 1.0000x reference)
//
#include <hip/hip_runtime.h>

// Problem constants (from reference)
#define N_NODES 100000
#define F_IN    128
#define H_DIM   128
#define Z_DIM   64
#define E_EDGES 1600000
#define EP_EDGES 200000

// bucket sort params: bucket = dst >> 7  (128 nodes/bucket)
#define BSHIFT 7
#define NBUCK  ((N_NODES + 127) >> 7)          // 782
#define CHUNK  4096
#define NCHUNK ((E_EDGES + CHUNK - 1) / CHUNK) // 391

typedef __attribute__((ext_vector_type(8))) short short8;   // 8 bf16 = 4 VGPRs
typedef __attribute__((ext_vector_type(4))) float f32x4;    // MFMA C/D frag
typedef unsigned int uint;
typedef unsigned short ushort;

// bf16 helpers (round-to-nearest-even)
__device__ __forceinline__ ushort f2bf(float f) {
    uint u = __float_as_uint(f);
    u += 0x7fffu + ((u >> 16) & 1u);
    return (ushort)(u >> 16);
}
__device__ __forceinline__ float bflo(uint u) { return __uint_as_float(u << 16); }
__device__ __forceinline__ float bfhi(uint u) { return __uint_as_float(u & 0xffff0000u); }

// ---------------- weight prep (+ gcur zeroing folded in) ----------------

__global__ __launch_bounds__(256) void wprep_kernel(const float* __restrict__ W1,
                                                    const float* __restrict__ W2,
                                                    ushort* __restrict__ W1T,
                                                    ushort* __restrict__ W2T,
                                                    int* __restrict__ gcur) {
    int i = blockIdx.x * 256 + threadIdx.x;
    if (i < 1024) gcur[i] = 0;               // zero bucket totals
    if (i < 128 * 128) {
        int n = i >> 7, k = i & 127;
        W1T[i] = f2bf(W1[k * 128 + n]);
    }
    int j = i - 128 * 128;
    if (j >= 0 && j < 64 * 128) {
        int n = j >> 7, k = j & 127;
        W2T[j] = f2bf(W2[k * 64 + n]);
    }
}

// ---------------- bucket histogram: per-chunk LDS hist -> tbl + totals -----
// tbl[c*NBUCK + b] = count of bucket b in chunk c (coalesced write).
// gcur[b] accumulates bucket totals (global atomics, 782/block).

__global__ __launch_bounds__(256) void bhist_kernel(const int* __restrict__ dst,
                                                    int* __restrict__ gcur,
                                                    int* __restrict__ tbl) {
    __shared__ int lh[NBUCK];
    for (int i = threadIdx.x; i < NBUCK; i += 256) lh[i] = 0;
    __syncthreads();
    int base = blockIdx.x * CHUNK;
    int end = min(base + CHUNK, E_EDGES);
    for (int e = base + threadIdx.x; e < end; e += 256)
        atomicAdd(&lh[dst[e] >> BSHIFT], 1);
    __syncthreads();
    int* trow = tbl + (size_t)blockIdx.x * NBUCK;
    for (int i = threadIdx.x; i < NBUCK; i += 256) {
        int c = lh[i];
        trow[i] = c;                         // per-chunk count (coalesced)
        if (c) atomicAdd(&gcur[i], c);       // bucket total
    }
}

// ---------------- exclusive scan over 782 bucket totals (single block) -----
// gcur[b] -> start offset of bucket b. Never mutated afterwards.

__global__ __launch_bounds__(1024) void bscan_kernel(int* __restrict__ gc) {
    __shared__ int s[1024];
    int t = threadIdx.x;
    int v = (t < NBUCK) ? gc[t] : 0;
    s[t] = v;
    __syncthreads();
    #pragma unroll
    for (int off = 1; off < 1024; off <<= 1) {
        int x = (t >= off) ? s[t - off] : 0;
        __syncthreads();
        s[t] += x;
        __syncthreads();
    }
    if (t < NBUCK) gc[t] = s[t] - v;   // exclusive prefix = bucket starts
}

// ---------------- per-bucket scan over chunk counts ----------------
// One block per bucket b: tbl[c][b] -> absolute base offset for (chunk c, b).

__global__ __launch_bounds__(512) void chunk_scan_kernel(int* __restrict__ tbl,
                                                         const int* __restrict__ gcur) {
    __shared__ int s[512];
    int b = blockIdx.x, t = threadIdx.x;
    int v = (t < NCHUNK) ? tbl[(size_t)t * NBUCK + b] : 0;
    s[t] = v;
    __syncthreads();
    #pragma unroll
    for (int off = 1; off < 512; off <<= 1) {
        int x = (t >= off) ? s[t - off] : 0;
        __syncthreads();
        s[t] += x;
        __syncthreads();
    }
    if (t < NCHUNK)
        tbl[(size_t)t * NBUCK + b] = gcur[b] + (s[t] - v);  // absolute base
}

// ---------------- bucket scatter: single pass, no global atomics -----------
// packed = (src << 7) | (dst & 127): src < 2^17, local dst 7 bits.

__global__ __launch_bounds__(256) void bscatter_kernel(const int* __restrict__ src,
                                                       const int* __restrict__ dst,
                                                       const int* __restrict__ tbl,
                                                       int* __restrict__ sorted) {
    __shared__ int lbase[NBUCK];
    int c = blockIdx.x;
    const int* trow = tbl + (size_t)c * NBUCK;
    for (int i = threadIdx.x; i < NBUCK; i += 256) lbase[i] = trow[i];  // coalesced
    __syncthreads();
    int base = c * CHUNK;
    int end = min(base + CHUNK, E_EDGES);
    for (int e = base + threadIdx.x; e < end; e += 256) {
        int d = dst[e];
        int p = atomicAdd(&lbase[d >> BSHIFT], 1);
        sorted[p] = (src[e] << 7) | (d & 127);
    }
}

// ---------------- fused per-bucket CSR build (per-wave hist/cursors) -------
// One block per bucket (128 nodes). Per-wave LDS histograms (4x fewer
// same-address conflicts) -> wave-0 scan folds per-wave bases -> ends[],
// dinv[], then node-grouped csr[] scatter on per-wave cursors.

__global__ __launch_bounds__(256) void bucket_csr_kernel(const int* __restrict__ sorted,
                                                         const int* __restrict__ gcur,
                                                         int* __restrict__ csr,
                                                         int* __restrict__ ends,
                                                         float* __restrict__ dinv) {
    __shared__ int lcnt[4][128], lcur[4][128];
    int b = blockIdx.x, t = threadIdx.x;
    int wave = t >> 6, lane = t & 63;
    int bstart = gcur[b];
    int bend = (b + 1 < NBUCK) ? gcur[b + 1] : E_EDGES;
    if (t < 128) { lcnt[0][t] = 0; lcnt[1][t] = 0; }
    else { int u = t - 128; lcnt[2][u] = 0; lcnt[3][u] = 0; }
    __syncthreads();
    for (int i = bstart + t; i < bend; i += 256)
        atomicAdd(&lcnt[wave][sorted[i] & 127], 1);
    __syncthreads();
    if (t < 64) {                         // wave 0: scan 128 node totals
        int w0a = lcnt[0][t], w1a = lcnt[1][t], w2a = lcnt[2][t], w3a = lcnt[3][t];
        int w0b = lcnt[0][t + 64], w1b = lcnt[1][t + 64], w2b = lcnt[2][t + 64], w3b = lcnt[3][t + 64];
        int c0 = w0a + w1a + w2a + w3a;
        int c1 = w0b + w1b + w2b + w3b;
        int s0 = c0;
        #pragma unroll
        for (int d = 1; d < 64; d <<= 1) {
            int x = __shfl_up(s0, d, 64);
            if (t >= d) s0 += x;
        }
        int tot0 = __shfl(s0, 63, 64);
        int s1 = c1;
        #pragma unroll
        for (int d = 1; d < 64; d <<= 1) {
            int x = __shfl_up(s1, d, 64);
            if (t >= d) s1 += x;
        }
        s1 += tot0;
        int basea = bstart + s0 - c0;     // start of node t
        int baseb = bstart + s1 - c1;     // start of node t+64
        lcur[0][t] = basea;
        lcur[1][t] = basea + w0a;
        lcur[2][t] = basea + w0a + w1a;
        lcur[3][t] = basea + w0a + w1a + w2a;
        lcur[0][t + 64] = baseb;
        lcur[1][t + 64] = baseb + w0b;
        lcur[2][t + 64] = baseb + w0b + w1b;
        lcur[3][t + 64] = baseb + w0b + w1b + w2b;
        int n0 = b * 128 + t, n1 = n0 + 64;
        if (n0 < N_NODES) { ends[n0] = bstart + s0; dinv[n0] = rsqrtf(1.0f + (float)c0); }
        if (n1 < N_NODES) { ends[n1] = bstart + s1; dinv[n1] = rsqrtf(1.0f + (float)c1); }
    }
    __syncthreads();
    for (int i = bstart + t; i < bend; i += 256) {
        int v = sorted[i];
        int p = atomicAdd(&lcur[wave][v & 127], 1);
        csr[p] = v >> 7;
    }
}

// ---------------- MFMA bf16 GEMM with dinv-prescaled bf16 output ----------
// C[row] = (A[row] @ B) * dinv[row], bf16. A fp32 (converted in-register) or bf16.

template<int NC, bool A_F32>
__global__ __launch_bounds__(256) void gemm_mfma_kernel(const void* __restrict__ Ap,
                                                        const ushort* __restrict__ BT,
                                                        const float* __restrict__ dinv,
                                                        ushort* __restrict__ C, int M) {
    constexpr int NT = NC / 16;
    __shared__ ushort Bs[4 * NT * 64 * 8];   // 32KB (NC=128) / 16KB (NC=64)

    for (int idx = threadIdx.x; idx < 4 * NT * 64; idx += 256) {
        int l   = idx & 63;
        int nt  = (idx >> 6) % NT;
        int kc  = idx / (64 * NT);
        int m16 = l & 15, quad = l >> 4;
        ((short8*)Bs)[idx] =
            *(const short8*)(BT + ((nt * 16 + m16) * 128 + kc * 32 + quad * 8));
    }
    __syncthreads();

    int wave = threadIdx.x >> 6, lane = threadIdx.x & 63;
    int m16 = lane & 15, quad = lane >> 4;
    int row0 = (blockIdx.x * 4 + wave) * 16;
    if (row0 >= M) return;
    int arow = row0 + m16;
    if (arow >= M) arow = M - 1;           // clamp loads; stores guarded

    f32x4 acc[NT];
    #pragma unroll
    for (int t = 0; t < NT; ++t) acc[t] = (f32x4){0.f, 0.f, 0.f, 0.f};

    #pragma unroll
    for (int kc = 0; kc < 4; ++kc) {
        short8 a;
        if (A_F32) {
            const float* A = (const float*)Ap;
            const float4* p = (const float4*)(A + (size_t)arow * 128 + kc * 32 + quad * 8);
            float4 x0 = p[0], x1 = p[1];
            a[0] = (short)f2bf(x0.x); a[1] = (short)f2bf(x0.y);
            a[2] = (short)f2bf(x0.z); a[3] = (short)f2bf(x0.w);
            a[4] = (short)f2bf(x1.x); a[5] = (short)f2bf(x1.y);
            a[6] = (short)f2bf(x1.z); a[7] = (short)f2bf(x1.w);
        } else {
            a = *(const short8*)((const ushort*)Ap + (size_t)arow * 128 + kc * 32 + quad * 8);
        }
        #pragma unroll
        for (int nt = 0; nt < NT; ++nt) {
            short8 b = ((const short8*)Bs)[(kc * NT + nt) * 64 + lane];
            acc[nt] = __builtin_amdgcn_mfma_f32_16x16x32_bf16(a, b, acc[nt], 0, 0, 0);
        }
    }

    #pragma unroll
    for (int r = 0; r < 4; ++r) {
        int row = row0 + quad * 4 + r;
        if (row < M) {
            float dr = dinv[row];
            #pragma unroll
            for (int nt = 0; nt < NT; ++nt)
                C[(size_t)row * NC + nt * 16 + m16] = f2bf(acc[nt][r] * dr);
        }
    }
}

// ---------------- gather FD=128: half-wave edge pairing, deep unroll -------
// out[n] = relu(bias + dinv[n] * (featS[n] + sum_j featS[csr[j]]))  (bf16 out)

__global__ __launch_bounds__(256) void gather128_kernel(const ushort* __restrict__ feat,
                                                        const float* __restrict__ bias,
                                                        const float* __restrict__ dinv,
                                                        const int* __restrict__ ends,
                                                        const int* __restrict__ csr,
                                                        ushort* __restrict__ out) {
    int wave = threadIdx.x >> 6, lane = threadIdx.x & 63;
    int half = lane >> 5, sl = lane & 31;
    int n = blockIdx.x * 4 + wave;
    const uint2* fu = (const uint2*)feat;   // row = 32 x uint2 (256B)

    float a0 = 0.f, a1 = 0.f, a2 = 0.f, a3 = 0.f;
    if (half == 0) {                        // self row counted once
        uint2 s = fu[(size_t)n * 32 + sl];
        a0 = bflo(s.x); a1 = bfhi(s.x); a2 = bflo(s.y); a3 = bfhi(s.y);
    }
    int j0 = n ? ends[n - 1] : 0, j1 = ends[n];
    int j = j0 + half;
    for (; j + 14 < j1; j += 16) {          // 8 rows in flight per half
        int s0 = csr[j],      s1 = csr[j + 2],  s2 = csr[j + 4],  s3 = csr[j + 6];
        int s4 = csr[j + 8],  s5 = csr[j + 10], s6 = csr[j + 12], s7 = csr[j + 14];
        uint2 f0 = fu[(size_t)s0 * 32 + sl];
        uint2 f1 = fu[(size_t)s1 * 32 + sl];
        uint2 f2 = fu[(size_t)s2 * 32 + sl];
        uint2 f3 = fu[(size_t)s3 * 32 + sl];
        uint2 f4 = fu[(size_t)s4 * 32 + sl];
        uint2 f5 = fu[(size_t)s5 * 32 + sl];
        uint2 f6 = fu[(size_t)s6 * 32 + sl];
        uint2 f7 = fu[(size_t)s7 * 32 + sl];
        a0 += bflo(f0.x) + bflo(f1.x) + bflo(f2.x) + bflo(f3.x)
            + bflo(f4.x) + bflo(f5.x) + bflo(f6.x) + bflo(f7.x);
        a1 += bfhi(f0.x) + bfhi(f1.x) + bfhi(f2.x) + bfhi(f3.x)
            + bfhi(f4.x) + bfhi(f5.x) + bfhi(f6.x) + bfhi(f7.x);
        a2 += bflo(f0.y) + bflo(f1.y) + bflo(f2.y) + bflo(f3.y)
            + bflo(f4.y) + bflo(f5.y) + bflo(f6.y) + bflo(f7.y);
        a3 += bfhi(f0.y) + bfhi(f1.y) + bfhi(f2.y) + bfhi(f3.y)
            + bfhi(f4.y) + bfhi(f5.y) + bfhi(f6.y) + bfhi(f7.y);
    }
    for (; j + 6 < j1; j += 8) {
        int s0 = csr[j], s1 = csr[j + 2], s2 = csr[j + 4], s3 = csr[j + 6];
        uint2 f0 = fu[(size_t)s0 * 32 + sl];
        uint2 f1 = fu[(size_t)s1 * 32 + sl];
        uint2 f2 = fu[(size_t)s2 * 32 + sl];
        uint2 f3 = fu[(size_t)s3 * 32 + sl];
        a0 += bflo(f0.x) + bflo(f1.x) + bflo(f2.x) + bflo(f3.x);
        a1 += bfhi(f0.x) + bfhi(f1.x) + bfhi(f2.x) + bfhi(f3.x);
        a2 += bflo(f0.y) + bflo(f1.y) + bflo(f2.y) + bflo(f3.y);
        a3 += bfhi(f0.y) + bfhi(f1.y) + bfhi(f2.y) + bfhi(f3.y);
    }
    for (; j < j1; j += 2) {
        uint2 f = fu[(size_t)csr[j] * 32 + sl];
        a0 += bflo(f.x); a1 += bfhi(f.x); a2 += bflo(f.y); a3 += bfhi(f.y);
    }
    a0 += __shfl_xor(a0, 32, 64);
    a1 += __shfl_xor(a1, 32, 64);
    a2 += __shfl_xor(a2, 32, 64);
    a3 += __shfl_xor(a3, 32, 64);
    if (half == 0) {
        float dn = dinv[n];
        float r0 = fmaxf(bias[sl * 4 + 0] + dn * a0, 0.f);
        float r1 = fmaxf(bias[sl * 4 + 1] + dn * a1, 0.f);
        float r2 = fmaxf(bias[sl * 4 + 2] + dn * a2, 0.f);
        float r3 = fmaxf(bias[sl * 4 + 3] + dn * a3, 0.f);
        uint2 o;
        o.x = (uint)f2bf(r0) | ((uint)f2bf(r1) << 16);
        o.y = (uint)f2bf(r2) | ((uint)f2bf(r3) << 16);
        ((uint2*)out)[(size_t)n * 32 + sl] = o;
    }
}

// ---------------- gather FD=64: half-wave pairing, packed bf16 latent out --

__global__ __launch_bounds__(256) void gather64_kernel(const ushort* __restrict__ feat,
                                                       const float* __restrict__ bias,
                                                       const float* __restrict__ dinv,
                                                       const int* __restrict__ ends,
                                                       const int* __restrict__ csr,
                                                       ushort* __restrict__ outB) {
    int wave = threadIdx.x >> 6, lane = threadIdx.x & 63;
    int half = lane >> 5, sl = lane & 31;
    int n = blockIdx.x * 4 + wave;
    const uint* fu = (const uint*)feat;     // row = 32 x uint (128B)

    float a0 = 0.f, a1 = 0.f;
    if (half == 0) {
        uint s = fu[(size_t)n * 32 + sl];
        a0 = bflo(s); a1 = bfhi(s);
    }
    int j0 = n ? ends[n - 1] : 0, j1 = ends[n];
    int j = j0 + half;
    for (; j + 14 < j1; j += 16) {          // 8 rows in flight per half
        int s0 = csr[j],      s1 = csr[j + 2],  s2 = csr[j + 4],  s3 = csr[j + 6];
        int s4 = csr[j + 8],  s5 = csr[j + 10], s6 = csr[j + 12], s7 = csr[j + 14];
        uint f0 = fu[(size_t)s0 * 32 + sl];
        uint f1 = fu[(size_t)s1 * 32 + sl];
        uint f2 = fu[(size_t)s2 * 32 + sl];
        uint f3 = fu[(size_t)s3 * 32 + sl];
        uint f4 = fu[(size_t)s4 * 32 + sl];
        uint f5 = fu[(size_t)s5 * 32 + sl];
        uint f6 = fu[(size_t)s6 * 32 + sl];
        uint f7 = fu[(size_t)s7 * 32 + sl];
        a0 += bflo(f0) + bflo(f1) + bflo(f2) + bflo(f3)
            + bflo(f4) + bflo(f5) + bflo(f6) + bflo(f7);
        a1 += bfhi(f0) + bfhi(f1) + bfhi(f2) + bfhi(f3)
            + bfhi(f4) + bfhi(f5) + bfhi(f6) + bfhi(f7);
    }
    for (; j + 6 < j1; j += 8) {
        int s0 = csr[j], s1 = csr[j + 2], s2 = csr[j + 4], s3 = csr[j + 6];
        uint f0 = fu[(size_t)s0 * 32 + sl];
        uint f1 = fu[(size_t)s1 * 32 + sl];
        uint f2 = fu[(size_t)s2 * 32 + sl];
        uint f3 = fu[(size_t)s3 * 32 + sl];
        a0 += bflo(f0) + bflo(f1) + bflo(f2) + bflo(f3);
        a1 += bfhi(f0) + bfhi(f1) + bfhi(f2) + bfhi(f3);
    }
    for (; j < j1; j += 2) {
        uint f = fu[(size_t)csr[j] * 32 + sl];
        a0 += bflo(f); a1 += bfhi(f);
    }
    a0 += __shfl_xor(a0, 32, 64);
    a1 += __shfl_xor(a1, 32, 64);
    if (half == 0) {
        float dn = dinv[n];
        float o0 = bias[sl * 2]     + dn * a0;
        float o1 = bias[sl * 2 + 1] + dn * a1;
        ((uint*)outB)[(size_t)n * 32 + sl] = (uint)f2bf(o0) | ((uint)f2bf(o1) << 16);
    }
}

// ---------------- decoder: bf16 latent, half-wave per edge, 8 edges/wave ---

__global__ __launch_bounds__(256) void decode_kernel(const ushort* __restrict__ latentB,
                                                     const int* __restrict__ pos,
                                                     const int* __restrict__ neg,
                                                     float* __restrict__ out) {
    int gwave = (blockIdx.x * 256 + threadIdx.x) >> 6;
    int lane = threadIdx.x & 63;
    int half = lane >> 5, sl = lane & 31;
    const uint* L = (const uint*)latentB;
    int e0 = gwave * 8 + half * 4;
    if (e0 >= 2 * EP_EDGES) return;

    int ia[4], ib[4];
    #pragma unroll
    for (int u = 0; u < 4; ++u) {
        int edge = e0 + u;
        if (edge < EP_EDGES) {
            ia[u] = pos[edge];
            ib[u] = pos[EP_EDGES + edge];
        } else {
            int e2 = edge - EP_EDGES;
            ia[u] = neg[e2];
            ib[u] = neg[EP_EDGES + e2];
        }
    }
    uint la[4], lb[4];
    #pragma unroll
    for (int u = 0; u < 4; ++u) {
        la[u] = L[(size_t)ia[u] * 32 + sl];
        lb[u] = L[(size_t)ib[u] * 32 + sl];
    }
    float v[4];
    #pragma unroll
    for (int u = 0; u < 4; ++u)
        v[u] = bflo(la[u]) * bflo(lb[u]) + bfhi(la[u]) * bfhi(lb[u]);
    #pragma unroll
    for (int u = 0; u < 4; ++u) {
        float s = v[u];
        #pragma unroll
        for (int off = 16; off > 0; off >>= 1) s += __shfl_down(s, off, 64);
        if (sl == 0) out[e0 + u] = s;   // lane 0 (half 0) and lane 32 (half 1)
    }
}

// ---------------- launcher ----------------

extern "C" void kernel_launch(void* const* d_in, const int* in_sizes, int n_in,
                              void* d_out, int out_size, void* d_ws, size_t ws_size,
                              hipStream_t stream) {
    const float* x  = (const float*)d_in[0];     // [N,128]
    const float* W1 = (const float*)d_in[1];     // [128,128]
    const float* b1 = (const float*)d_in[2];     // [128]
    const float* W2 = (const float*)d_in[3];     // [128,64]
    const float* b2 = (const float*)d_in[4];     // [64]
    const int* edge_index = (const int*)d_in[5]; // [2,E] flat
    const int* pos = (const int*)d_in[6];        // [2,EP] flat
    const int* neg = (const int*)d_in[7];        // [2,EP] flat
    float* out = (float*)d_out;                  // [2*EP]

    const int* src = edge_index;
    const int* dst = edge_index + E_EDGES;

    // ws: dinv[N] | ends[N] | gcur[1024] | tbl[NCHUNK*NBUCK] | sorted[E] |
    //     csr[E] | W1T | W2T | bufH[N*128] bf16 | bufR[N*128] bf16
    float*  dinv   = (float*)d_ws;
    int*    ends   = (int*)(dinv + N_NODES);
    int*    gcur   = ends + N_NODES;
    int*    tbl    = gcur + 1024;
    int*    sorted = tbl + NCHUNK * NBUCK;
    int*    csr    = sorted + E_EDGES;
    ushort* W1T    = (ushort*)(csr + E_EDGES);
    ushort* W2T    = W1T + 128 * 128;
    ushort* bufH   = W2T + 64 * 128;
    ushort* bufR   = bufH + (size_t)N_NODES * 128;

    // 1) weights -> bf16 transposed (+ gcur zeroing)
    wprep_kernel<<<96, 256, 0, stream>>>(W1, W2, W1T, W2T, gcur);

    // 2) deterministic bucket sort: hist -> bucket scan -> chunk scan -> scatter
    bhist_kernel<<<NCHUNK, 256, 0, stream>>>(dst, gcur, tbl);
    bscan_kernel<<<1, 1024, 0, stream>>>(gcur);
    chunk_scan_kernel<<<NBUCK, 512, 0, stream>>>(tbl, gcur);
    bscatter_kernel<<<NCHUNK, 256, 0, stream>>>(src, dst, tbl, sorted);
    bucket_csr_kernel<<<NBUCK, 256, 0, stream>>>(sorted, gcur, csr, ends, dinv);

    const int GEMM_GRID = (N_NODES + 63) / 64;

    // 3) h0_s = (x @ W1) * dinv  (fp32 A converted in-register) -> bufH bf16
    gemm_mfma_kernel<128, true><<<GEMM_GRID, 256, 0, stream>>>(x, W1T, dinv, bufH, N_NODES);

    // 4) h_relu = relu(b1 + dinv * (self + Agg)) -> bufR bf16
    gather128_kernel<<<N_NODES / 4, 256, 0, stream>>>(bufH, b1, dinv, ends, csr, bufR);

    // 5) l0_s = (h_relu @ W2) * dinv -> bufH bf16 [N,64]
    gemm_mfma_kernel<64, false><<<GEMM_GRID, 256, 0, stream>>>(bufR, W2T, dinv, bufH, N_NODES);

    // 6) latentB = b2 + dinv * (self + Agg) -> bufR packed bf16 [N,64]
    ushort* latentB = bufR;
    gather64_kernel<<<N_NODES / 4, 256, 0, stream>>>(bufH, b2, dinv, ends, csr, latentB);

    // 7) decode on bf16 latent: 8 edges per wave -> 12500 blocks
    decode_kernel<<<(2 * EP_EDGES) / 32, 256, 0, stream>>>(latentB, pos, neg, out);
}

// Round 12
// 320.300 us; speedup vs baseline: 1.0899x; 1.0899x over previous
//
#include <hip/hip_runtime.h>

// Problem constants (from reference)
#define N_NODES 100000
#define F_IN    128
#define H_DIM   128
#define Z_DIM   64
#define E_EDGES 1600000
#define EP_EDGES 200000

// bucket sort params: bucket = dst >> 7  (128 nodes/bucket)
#define BSHIFT 7
#define NBUCK  ((N_NODES + 127) >> 7)          // 782
#define CHUNK  4096
#define NCHUNK ((E_EDGES + CHUNK - 1) / CHUNK) // 391

typedef __attribute__((ext_vector_type(8))) short short8;   // 8 bf16 = 4 VGPRs
typedef __attribute__((ext_vector_type(4))) float f32x4;    // MFMA C/D frag
typedef unsigned int uint;
typedef unsigned short ushort;

// bf16 helpers (round-to-nearest-even)
__device__ __forceinline__ ushort f2bf(float f) {
    uint u = __float_as_uint(f);
    u += 0x7fffu + ((u >> 16) & 1u);
    return (ushort)(u >> 16);
}
__device__ __forceinline__ float bflo(uint u) { return __uint_as_float(u << 16); }
__device__ __forceinline__ float bfhi(uint u) { return __uint_as_float(u & 0xffff0000u); }

// ---------------- weight prep (+ gcur zeroing folded in) ----------------

__global__ __launch_bounds__(256) void wprep_kernel(const float* __restrict__ W1,
                                                    const float* __restrict__ W2,
                                                    ushort* __restrict__ W1T,
                                                    ushort* __restrict__ W2T,
                                                    int* __restrict__ gcur) {
    int i = blockIdx.x * 256 + threadIdx.x;
    if (i < 1024) gcur[i] = 0;               // zero bucket totals
    if (i < 128 * 128) {
        int n = i >> 7, k = i & 127;
        W1T[i] = f2bf(W1[k * 128 + n]);
    }
    int j = i - 128 * 128;
    if (j >= 0 && j < 64 * 128) {
        int n = j >> 7, k = j & 127;
        W2T[j] = f2bf(W2[k * 64 + n]);
    }
}

// ---------------- bucket histogram: per-chunk LDS hist -> tbl + totals -----

__global__ __launch_bounds__(256) void bhist_kernel(const int* __restrict__ dst,
                                                    int* __restrict__ gcur,
                                                    int* __restrict__ tbl) {
    __shared__ int lh[NBUCK];
    for (int i = threadIdx.x; i < NBUCK; i += 256) lh[i] = 0;
    __syncthreads();
    int base = blockIdx.x * CHUNK;
    int end = min(base + CHUNK, E_EDGES);
    for (int e = base + threadIdx.x; e < end; e += 256)
        atomicAdd(&lh[dst[e] >> BSHIFT], 1);
    __syncthreads();
    int* trow = tbl + (size_t)blockIdx.x * NBUCK;
    for (int i = threadIdx.x; i < NBUCK; i += 256) {
        int c = lh[i];
        trow[i] = c;                         // per-chunk count (coalesced)
        if (c) atomicAdd(&gcur[i], c);       // bucket total
    }
}

// ---------------- exclusive scan over 782 bucket totals (single block) -----

__global__ __launch_bounds__(1024) void bscan_kernel(int* __restrict__ gc) {
    __shared__ int s[1024];
    int t = threadIdx.x;
    int v = (t < NBUCK) ? gc[t] : 0;
    s[t] = v;
    __syncthreads();
    #pragma unroll
    for (int off = 1; off < 1024; off <<= 1) {
        int x = (t >= off) ? s[t - off] : 0;
        __syncthreads();
        s[t] += x;
        __syncthreads();
    }
    if (t < NBUCK) gc[t] = s[t] - v;   // exclusive prefix = bucket starts
}

// ---------------- per-bucket scan over chunk counts ----------------

__global__ __launch_bounds__(512) void chunk_scan_kernel(int* __restrict__ tbl,
                                                         const int* __restrict__ gcur) {
    __shared__ int s[512];
    int b = blockIdx.x, t = threadIdx.x;
    int v = (t < NCHUNK) ? tbl[(size_t)t * NBUCK + b] : 0;
    s[t] = v;
    __syncthreads();
    #pragma unroll
    for (int off = 1; off < 512; off <<= 1) {
        int x = (t >= off) ? s[t - off] : 0;
        __syncthreads();
        s[t] += x;
        __syncthreads();
    }
    if (t < NCHUNK)
        tbl[(size_t)t * NBUCK + b] = gcur[b] + (s[t] - v);  // absolute base
}

// ---------------- bucket scatter: single pass, no global atomics -----------
// packed = (src << 7) | (dst & 127): src < 2^17, local dst 7 bits.

__global__ __launch_bounds__(256) void bscatter_kernel(const int* __restrict__ src,
                                                       const int* __restrict__ dst,
                                                       const int* __restrict__ tbl,
                                                       int* __restrict__ sorted) {
    __shared__ int lbase[NBUCK];
    int c = blockIdx.x;
    const int* trow = tbl + (size_t)c * NBUCK;
    for (int i = threadIdx.x; i < NBUCK; i += 256) lbase[i] = trow[i];  // coalesced
    __syncthreads();
    int base = c * CHUNK;
    int end = min(base + CHUNK, E_EDGES);
    for (int e = base + threadIdx.x; e < end; e += 256) {
        int d = dst[e];
        int p = atomicAdd(&lbase[d >> BSHIFT], 1);
        sorted[p] = (src[e] << 7) | (d & 127);
    }
}

// ---------------- fused per-bucket CSR build (per-wave hist/cursors) -------

__global__ __launch_bounds__(256) void bucket_csr_kernel(const int* __restrict__ sorted,
                                                         const int* __restrict__ gcur,
                                                         int* __restrict__ csr,
                                                         int* __restrict__ ends,
                                                         float* __restrict__ dinv) {
    __shared__ int lcnt[4][128], lcur[4][128];
    int b = blockIdx.x, t = threadIdx.x;
    int wave = t >> 6;
    int bstart = gcur[b];
    int bend = (b + 1 < NBUCK) ? gcur[b + 1] : E_EDGES;
    if (t < 128) { lcnt[0][t] = 0; lcnt[1][t] = 0; }
    else { int u = t - 128; lcnt[2][u] = 0; lcnt[3][u] = 0; }
    __syncthreads();
    for (int i = bstart + t; i < bend; i += 256)
        atomicAdd(&lcnt[wave][sorted[i] & 127], 1);
    __syncthreads();
    if (t < 64) {                         // wave 0: scan 128 node totals
        int w0a = lcnt[0][t], w1a = lcnt[1][t], w2a = lcnt[2][t], w3a = lcnt[3][t];
        int w0b = lcnt[0][t + 64], w1b = lcnt[1][t + 64], w2b = lcnt[2][t + 64], w3b = lcnt[3][t + 64];
        int c0 = w0a + w1a + w2a + w3a;
        int c1 = w0b + w1b + w2b + w3b;
        int s0 = c0;
        #pragma unroll
        for (int d = 1; d < 64; d <<= 1) {
            int x = __shfl_up(s0, d, 64);
            if (t >= d) s0 += x;
        }
        int tot0 = __shfl(s0, 63, 64);
        int s1 = c1;
        #pragma unroll
        for (int d = 1; d < 64; d <<= 1) {
            int x = __shfl_up(s1, d, 64);
            if (t >= d) s1 += x;
        }
        s1 += tot0;
        int basea = bstart + s0 - c0;     // start of node t
        int baseb = bstart + s1 - c1;     // start of node t+64
        lcur[0][t] = basea;
        lcur[1][t] = basea + w0a;
        lcur[2][t] = basea + w0a + w1a;
        lcur[3][t] = basea + w0a + w1a + w2a;
        lcur[0][t + 64] = baseb;
        lcur[1][t + 64] = baseb + w0b;
        lcur[2][t + 64] = baseb + w0b + w1b;
        lcur[3][t + 64] = baseb + w0b + w1b + w2b;
        int n0 = b * 128 + t, n1 = n0 + 64;
        if (n0 < N_NODES) { ends[n0] = bstart + s0; dinv[n0] = rsqrtf(1.0f + (float)c0); }
        if (n1 < N_NODES) { ends[n1] = bstart + s1; dinv[n1] = rsqrtf(1.0f + (float)c1); }
    }
    __syncthreads();
    for (int i = bstart + t; i < bend; i += 256) {
        int v = sorted[i];
        int p = atomicAdd(&lcur[wave][v & 127], 1);
        csr[p] = v >> 7;
    }
}

// ---------------- MFMA bf16 GEMM with dinv-prescaled bf16 output ----------

template<int NC, bool A_F32>
__global__ __launch_bounds__(256) void gemm_mfma_kernel(const void* __restrict__ Ap,
                                                        const ushort* __restrict__ BT,
                                                        const float* __restrict__ dinv,
                                                        ushort* __restrict__ C, int M) {
    constexpr int NT = NC / 16;
    __shared__ ushort Bs[4 * NT * 64 * 8];   // 32KB (NC=128) / 16KB (NC=64)

    for (int idx = threadIdx.x; idx < 4 * NT * 64; idx += 256) {
        int l   = idx & 63;
        int nt  = (idx >> 6) % NT;
        int kc  = idx / (64 * NT);
        int m16 = l & 15, quad = l >> 4;
        ((short8*)Bs)[idx] =
            *(const short8*)(BT + ((nt * 16 + m16) * 128 + kc * 32 + quad * 8));
    }
    __syncthreads();

    int wave = threadIdx.x >> 6, lane = threadIdx.x & 63;
    int m16 = lane & 15, quad = lane >> 4;
    int row0 = (blockIdx.x * 4 + wave) * 16;
    if (row0 >= M) return;
    int arow = row0 + m16;
    if (arow >= M) arow = M - 1;           // clamp loads; stores guarded

    f32x4 acc[NT];
    #pragma unroll
    for (int t = 0; t < NT; ++t) acc[t] = (f32x4){0.f, 0.f, 0.f, 0.f};

    #pragma unroll
    for (int kc = 0; kc < 4; ++kc) {
        short8 a;
        if (A_F32) {
            const float* A = (const float*)Ap;
            const float4* p = (const float4*)(A + (size_t)arow * 128 + kc * 32 + quad * 8);
            float4 x0 = p[0], x1 = p[1];
            a[0] = (short)f2bf(x0.x); a[1] = (short)f2bf(x0.y);
            a[2] = (short)f2bf(x0.z); a[3] = (short)f2bf(x0.w);
            a[4] = (short)f2bf(x1.x); a[5] = (short)f2bf(x1.y);
            a[6] = (short)f2bf(x1.z); a[7] = (short)f2bf(x1.w);
        } else {
            a = *(const short8*)((const ushort*)Ap + (size_t)arow * 128 + kc * 32 + quad * 8);
        }
        #pragma unroll
        for (int nt = 0; nt < NT; ++nt) {
            short8 b = ((const short8*)Bs)[(kc * NT + nt) * 64 + lane];
            acc[nt] = __builtin_amdgcn_mfma_f32_16x16x32_bf16(a, b, acc[nt], 0, 0, 0);
        }
    }

    #pragma unroll
    for (int r = 0; r < 4; ++r) {
        int row = row0 + quad * 4 + r;
        if (row < M) {
            float dr = dinv[row];
            #pragma unroll
            for (int nt = 0; nt < NT; ++nt)
                C[(size_t)row * NC + nt * 16 + m16] = f2bf(acc[nt][r] * dr);
        }
    }
}

// ---------------- gather FD=128: half-wave edge pairing, deep unroll -------
// out[n] = relu(bias + dinv[n] * (featS[n] + sum_j featS[csr[j]]))  (bf16 out)

__global__ __launch_bounds__(256) void gather128_kernel(const ushort* __restrict__ feat,
                                                        const float* __restrict__ bias,
                                                        const float* __restrict__ dinv,
                                                        const int* __restrict__ ends,
                                                        const int* __restrict__ csr,
                                                        ushort* __restrict__ out) {
    int wave = threadIdx.x >> 6, lane = threadIdx.x & 63;
    int half = lane >> 5, sl = lane & 31;
    int n = blockIdx.x * 4 + wave;
    const uint2* fu = (const uint2*)feat;   // row = 32 x uint2 (256B)

    float a0 = 0.f, a1 = 0.f, a2 = 0.f, a3 = 0.f;
    if (half == 0) {                        // self row counted once
        uint2 s = fu[(size_t)n * 32 + sl];
        a0 = bflo(s.x); a1 = bfhi(s.x); a2 = bflo(s.y); a3 = bfhi(s.y);
    }
    int j0 = n ? ends[n - 1] : 0, j1 = ends[n];
    int j = j0 + half;
    for (; j + 14 < j1; j += 16) {          // 8 rows in flight per half
        int s0 = csr[j],      s1 = csr[j + 2],  s2 = csr[j + 4],  s3 = csr[j + 6];
        int s4 = csr[j + 8],  s5 = csr[j + 10], s6 = csr[j + 12], s7 = csr[j + 14];
        uint2 f0 = fu[(size_t)s0 * 32 + sl];
        uint2 f1 = fu[(size_t)s1 * 32 + sl];
        uint2 f2 = fu[(size_t)s2 * 32 + sl];
        uint2 f3 = fu[(size_t)s3 * 32 + sl];
        uint2 f4 = fu[(size_t)s4 * 32 + sl];
        uint2 f5 = fu[(size_t)s5 * 32 + sl];
        uint2 f6 = fu[(size_t)s6 * 32 + sl];
        uint2 f7 = fu[(size_t)s7 * 32 + sl];
        a0 += bflo(f0.x) + bflo(f1.x) + bflo(f2.x) + bflo(f3.x)
            + bflo(f4.x) + bflo(f5.x) + bflo(f6.x) + bflo(f7.x);
        a1 += bfhi(f0.x) + bfhi(f1.x) + bfhi(f2.x) + bfhi(f3.x)
            + bfhi(f4.x) + bfhi(f5.x) + bfhi(f6.x) + bfhi(f7.x);
        a2 += bflo(f0.y) + bflo(f1.y) + bflo(f2.y) + bflo(f3.y)
            + bflo(f4.y) + bflo(f5.y) + bflo(f6.y) + bflo(f7.y);
        a3 += bfhi(f0.y) + bfhi(f1.y) + bfhi(f2.y) + bfhi(f3.y)
            + bfhi(f4.y) + bfhi(f5.y) + bfhi(f6.y) + bfhi(f7.y);
    }
    for (; j + 6 < j1; j += 8) {
        int s0 = csr[j], s1 = csr[j + 2], s2 = csr[j + 4], s3 = csr[j + 6];
        uint2 f0 = fu[(size_t)s0 * 32 + sl];
        uint2 f1 = fu[(size_t)s1 * 32 + sl];
        uint2 f2 = fu[(size_t)s2 * 32 + sl];
        uint2 f3 = fu[(size_t)s3 * 32 + sl];
        a0 += bflo(f0.x) + bflo(f1.x) + bflo(f2.x) + bflo(f3.x);
        a1 += bfhi(f0.x) + bfhi(f1.x) + bfhi(f2.x) + bfhi(f3.x);
        a2 += bflo(f0.y) + bflo(f1.y) + bflo(f2.y) + bflo(f3.y);
        a3 += bfhi(f0.y) + bfhi(f1.y) + bfhi(f2.y) + bfhi(f3.y);
    }
    for (; j < j1; j += 2) {
        uint2 f = fu[(size_t)csr[j] * 32 + sl];
        a0 += bflo(f.x); a1 += bfhi(f.x); a2 += bflo(f.y); a3 += bfhi(f.y);
    }
    a0 += __shfl_xor(a0, 32, 64);
    a1 += __shfl_xor(a1, 32, 64);
    a2 += __shfl_xor(a2, 32, 64);
    a3 += __shfl_xor(a3, 32, 64);
    if (half == 0) {
        float dn = dinv[n];
        float r0 = fmaxf(bias[sl * 4 + 0] + dn * a0, 0.f);
        float r1 = fmaxf(bias[sl * 4 + 1] + dn * a1, 0.f);
        float r2 = fmaxf(bias[sl * 4 + 2] + dn * a2, 0.f);
        float r3 = fmaxf(bias[sl * 4 + 3] + dn * a3, 0.f);
        uint2 o;
        o.x = (uint)f2bf(r0) | ((uint)f2bf(r1) << 16);
        o.y = (uint)f2bf(r2) | ((uint)f2bf(r3) << 16);
        ((uint2*)out)[(size_t)n * 32 + sl] = o;
    }
}

// ---------------- gather FD=64: half-wave pairing, packed bf16 latent out --

__global__ __launch_bounds__(256) void gather64_kernel(const ushort* __restrict__ feat,
                                                       const float* __restrict__ bias,
                                                       const float* __restrict__ dinv,
                                                       const int* __restrict__ ends,
                                                       const int* __restrict__ csr,
                                                       ushort* __restrict__ outB) {
    int wave = threadIdx.x >> 6, lane = threadIdx.x & 63;
    int half = lane >> 5, sl = lane & 31;
    int n = blockIdx.x * 4 + wave;
    const uint* fu = (const uint*)feat;     // row = 32 x uint (128B)

    float a0 = 0.f, a1 = 0.f;
    if (half == 0) {
        uint s = fu[(size_t)n * 32 + sl];
        a0 = bflo(s); a1 = bfhi(s);
    }
    int j0 = n ? ends[n - 1] : 0, j1 = ends[n];
    int j = j0 + half;
    for (; j + 14 < j1; j += 16) {          // 8 rows in flight per half
        int s0 = csr[j],      s1 = csr[j + 2],  s2 = csr[j + 4],  s3 = csr[j + 6];
        int s4 = csr[j + 8],  s5 = csr[j + 10], s6 = csr[j + 12], s7 = csr[j + 14];
        uint f0 = fu[(size_t)s0 * 32 + sl];
        uint f1 = fu[(size_t)s1 * 32 + sl];
        uint f2 = fu[(size_t)s2 * 32 + sl];
        uint f3 = fu[(size_t)s3 * 32 + sl];
        uint f4 = fu[(size_t)s4 * 32 + sl];
        uint f5 = fu[(size_t)s5 * 32 + sl];
        uint f6 = fu[(size_t)s6 * 32 + sl];
        uint f7 = fu[(size_t)s7 * 32 + sl];
        a0 += bflo(f0) + bflo(f1) + bflo(f2) + bflo(f3)
            + bflo(f4) + bflo(f5) + bflo(f6) + bflo(f7);
        a1 += bfhi(f0) + bfhi(f1) + bfhi(f2) + bfhi(f3)
            + bfhi(f4) + bfhi(f5) + bfhi(f6) + bfhi(f7);
    }
    for (; j + 6 < j1; j += 8) {
        int s0 = csr[j], s1 = csr[j + 2], s2 = csr[j + 4], s3 = csr[j + 6];
        uint f0 = fu[(size_t)s0 * 32 + sl];
        uint f1 = fu[(size_t)s1 * 32 + sl];
        uint f2 = fu[(size_t)s2 * 32 + sl];
        uint f3 = fu[(size_t)s3 * 32 + sl];
        a0 += bflo(f0) + bflo(f1) + bflo(f2) + bflo(f3);
        a1 += bfhi(f0) + bfhi(f1) + bfhi(f2) + bfhi(f3);
    }
    for (; j < j1; j += 2) {
        uint f = fu[(size_t)csr[j] * 32 + sl];
        a0 += bflo(f); a1 += bfhi(f);
    }
    a0 += __shfl_xor(a0, 32, 64);
    a1 += __shfl_xor(a1, 32, 64);
    if (half == 0) {
        float dn = dinv[n];
        float o0 = bias[sl * 2]     + dn * a0;
        float o1 = bias[sl * 2 + 1] + dn * a1;
        ((uint*)outB)[(size_t)n * 32 + sl] = (uint)f2bf(o0) | ((uint)f2bf(o1) << 16);
    }
}

// ---------------- decoder: bf16 latent, half-wave per edge, 8 edges/wave ---

__global__ __launch_bounds__(256) void decode_kernel(const ushort* __restrict__ latentB,
                                                     const int* __restrict__ pos,
                                                     const int* __restrict__ neg,
                                                     float* __restrict__ out) {
    int gwave = (blockIdx.x * 256 + threadIdx.x) >> 6;
    int lane = threadIdx.x & 63;
    int half = lane >> 5, sl = lane & 31;
    const uint* L = (const uint*)latentB;
    int e0 = gwave * 8 + half * 4;
    if (e0 >= 2 * EP_EDGES) return;

    int ia[4], ib[4];
    #pragma unroll
    for (int u = 0; u < 4; ++u) {
        int edge = e0 + u;
        if (edge < EP_EDGES) {
            ia[u] = pos[edge];
            ib[u] = pos[EP_EDGES + edge];
        } else {
            int e2 = edge - EP_EDGES;
            ia[u] = neg[e2];
            ib[u] = neg[EP_EDGES + e2];
        }
    }
    uint la[4], lb[4];
    #pragma unroll
    for (int u = 0; u < 4; ++u) {
        la[u] = L[(size_t)ia[u] * 32 + sl];
        lb[u] = L[(size_t)ib[u] * 32 + sl];
    }
    float v[4];
    #pragma unroll
    for (int u = 0; u < 4; ++u)
        v[u] = bflo(la[u]) * bflo(lb[u]) + bfhi(la[u]) * bfhi(lb[u]);
    #pragma unroll
    for (int u = 0; u < 4; ++u) {
        float s = v[u];
        #pragma unroll
        for (int off = 16; off > 0; off >>= 1) s += __shfl_down(s, off, 64);
        if (sl == 0) out[e0 + u] = s;   // lane 0 (half 0) and lane 32 (half 1)
    }
}

// ---------------- launcher ----------------

extern "C" void kernel_launch(void* const* d_in, const int* in_sizes, int n_in,
                              void* d_out, int out_size, void* d_ws, size_t ws_size,
                              hipStream_t stream) {
    const float* x  = (const float*)d_in[0];     // [N,128]
    const float* W1 = (const float*)d_in[1];     // [128,128]
    const float* b1 = (const float*)d_in[2];     // [128]
    const float* W2 = (const float*)d_in[3];     // [128,64]
    const float* b2 = (const float*)d_in[4];     // [64]
    const int* edge_index = (const int*)d_in[5]; // [2,E] flat
    const int* pos = (const int*)d_in[6];        // [2,EP] flat
    const int* neg = (const int*)d_in[7];        // [2,EP] flat
    float* out = (float*)d_out;                  // [2*EP]

    const int* src = edge_index;
    const int* dst = edge_index + E_EDGES;

    // ws: dinv[N] | ends[N] | gcur[1024] | tbl[NCHUNK*NBUCK] | sorted[E] |
    //     csr[E] | W1T | W2T | [pad to 256B] | bufH[N*128] bf16 | bufR[N*128] bf16
    // bufH/bufR MUST be 256B-aligned: feature rows are 256B / 128B — R11's
    // misalignment (+1.2MB tbl shift) cost +43% FETCH in every random-row kernel.
    float*  dinv   = (float*)d_ws;
    int*    ends   = (int*)(dinv + N_NODES);
    int*    gcur   = ends + N_NODES;
    int*    tbl    = gcur + 1024;
    int*    sorted = tbl + NCHUNK * NBUCK;
    int*    csr    = sorted + E_EDGES;
    ushort* W1T    = (ushort*)(csr + E_EDGES);
    ushort* W2T    = W1T + 128 * 128;
    ushort* bufH   = (ushort*)(((uintptr_t)(W2T + 64 * 128) + 255) & ~(uintptr_t)255);
    ushort* bufR   = bufH + (size_t)N_NODES * 128;   // 25.6MB offset, stays 256B-aligned

    // 1) weights -> bf16 transposed (+ gcur zeroing)
    wprep_kernel<<<96, 256, 0, stream>>>(W1, W2, W1T, W2T, gcur);

    // 2) deterministic bucket sort: hist -> bucket scan -> chunk scan -> scatter
    bhist_kernel<<<NCHUNK, 256, 0, stream>>>(dst, gcur, tbl);
    bscan_kernel<<<1, 1024, 0, stream>>>(gcur);
    chunk_scan_kernel<<<NBUCK, 512, 0, stream>>>(tbl, gcur);
    bscatter_kernel<<<NCHUNK, 256, 0, stream>>>(src, dst, tbl, sorted);
    bucket_csr_kernel<<<NBUCK, 256, 0, stream>>>(sorted, gcur, csr, ends, dinv);

    const int GEMM_GRID = (N_NODES + 63) / 64;

    // 3) h0_s = (x @ W1) * dinv  (fp32 A converted in-register) -> bufH bf16
    gemm_mfma_kernel<128, true><<<GEMM_GRID, 256, 0, stream>>>(x, W1T, dinv, bufH, N_NODES);

    // 4) h_relu = relu(b1 + dinv * (self + Agg)) -> bufR bf16
    gather128_kernel<<<N_NODES / 4, 256, 0, stream>>>(bufH, b1, dinv, ends, csr, bufR);

    // 5) l0_s = (h_relu @ W2) * dinv -> bufH bf16 [N,64]
    gemm_mfma_kernel<64, false><<<GEMM_GRID, 256, 0, stream>>>(bufR, W2T, dinv, bufH, N_NODES);

    // 6) latentB = b2 + dinv * (self + Agg) -> bufR packed bf16 [N,64]
    ushort* latentB = bufR;
    gather64_kernel<<<N_NODES / 4, 256, 0, stream>>>(bufH, b2, dinv, ends, csr, latentB);

    // 7) decode on bf16 latent: 8 edges per wave -> 12500 blocks
    decode_kernel<<<(2 * EP_EDGES) / 32, 256, 0, stream>>>(latentB, pos, neg, out);
}